// Round 5
// baseline (2114.344 us; speedup 1.0000x reference)
//
#include <hip/hip_runtime.h>

typedef _Float16 f16x8 __attribute__((ext_vector_type(8)));
typedef float f32x16 __attribute__((ext_vector_type(16)));

__device__ __forceinline__ unsigned int fkey(float f) {
    unsigned int u = __float_as_uint(f);
    return u ^ ((u & 0x80000000u) ? 0xFFFFFFFFu : 0x80000000u);
}

// ============================================================
// Prep: split fp32 -> (hi, lo) f16 pairs. x kept row-major; di transposed.
// ============================================================
__global__ __launch_bounds__(256) void prep_x_kernel(
    const float* __restrict__ x, _Float16* __restrict__ Xh,
    _Float16* __restrict__ Xl)
{
    size_t base = ((size_t)blockIdx.x * 256 + threadIdx.x) * 8;
    float4 a0 = *(const float4*)(x + base);
    float4 a1 = *(const float4*)(x + base + 4);
    float v[8] = {a0.x, a0.y, a0.z, a0.w, a1.x, a1.y, a1.z, a1.w};
    f16x8 h, l;
#pragma unroll
    for (int j = 0; j < 8; ++j) {
        _Float16 hh = (_Float16)v[j];
        h[j] = hh;
        l[j] = (_Float16)(v[j] - (float)hh);   // residual exact in fp32
    }
    *(f16x8*)(Xh + base) = h;
    *(f16x8*)(Xl + base) = l;
}

__global__ __launch_bounds__(256) void prep_di_kernel(
    const float* __restrict__ di, _Float16* __restrict__ DhT,
    _Float16* __restrict__ DlT, int D, int V)
{
    int v  = blockIdx.x * 64 + (threadIdx.x & 63);
    int d0 = blockIdx.y * 32 + (threadIdx.x >> 6) * 8;
    f16x8 h, l;
#pragma unroll
    for (int j = 0; j < 8; ++j) {
        float val = di[(size_t)(d0 + j) * V + v];   // coalesced across lanes
        _Float16 hh = (_Float16)val;
        h[j] = hh;
        l[j] = (_Float16)(val - (float)hh);
    }
    *(f16x8*)(DhT + (size_t)v * D + d0) = h;
    *(f16x8*)(DlT + (size_t)v * D + d0) = l;
}

// ============================================================
// Main: 256x256 tile, BK=32, 8 waves (2x4), per-wave 128x64 output,
// v_mfma_f32_32x32x16_f16, 3 terms (ah*bh + ah*bl + al*bh).
// LDS layout per operand tile (16KB): addr(row,slot) =
//   (row>>5)*2048 + slot*512 + (row&31)*16,  slot = 16B k-slot (0..3).
// Produced linearly by global_load_lds (uniform dest, lane*16 auto) with
// per-lane source row = gg*32 + (lane&31), k-slot = sp*2 + (lane>>5).
// Frag reads are 512B-contiguous per 32-lane half -> 0 bank conflicts.
// Double-buffered 2x64KB, stage spread over phases 0-1, vmcnt(0) once
// per tile, 1 barrier per phase, setprio around MFMA clusters.
// ============================================================
__global__ __launch_bounds__(512, 2) void gemm_f16x3_argmax_256(
    const _Float16* __restrict__ Xh, const _Float16* __restrict__ Xl,
    const _Float16* __restrict__ DhT, const _Float16* __restrict__ DlT,
    unsigned long long* __restrict__ best, int N, int D, int V)
{
    extern __shared__ __align__(16) unsigned char sm[];   // 2 x 65536

    const int tid = threadIdx.x;
    const int w = tid >> 6, lane = tid & 63;
    const int wr = w >> 2, wc = w & 3;          // 2x4 wave grid
    const int l31 = lane & 31, hl = lane >> 5;

    // bijective XCD swizzle (2048 blocks, 2048 % 8 == 0)
    const int cpx = gridDim.x >> 3;
    const int swz = (blockIdx.x & 7) * cpx + (blockIdx.x >> 3);
    const int bm = (swz >> 5) * 256;            // 64 m-tiles
    const int bn = (swz & 31) * 256;            // 32 n-tiles

    const _Float16* opsrc[4] = {
        Xh  + (size_t)bm * D,
        Xl  + (size_t)bm * D,
        DhT + (size_t)bn * D,
        DlT + (size_t)bn * D };

    // wave w stages chunks g = w*8 + half*4 + i; op = g>>4, c = g&15.
    // chunk c: row-group gg = c>>1, slot-pair sp = c&1.
    auto stage4 = [&](int buf, int k0, int half) {
#pragma unroll
        for (int i = 0; i < 4; ++i) {
            const int g = w * 8 + half * 4 + i;
            const int op = g >> 4, c = g & 15;
            const int gg = c >> 1, sp = c & 1;
            __builtin_amdgcn_global_load_lds(
                (const __attribute__((address_space(1))) void*)
                    (opsrc[op] + (size_t)(gg * 32 + l31) * D + k0 + (sp * 2 + hl) * 8),
                (__attribute__((address_space(3))) void*)
                    (sm + buf * 65536 + op * 16384 + c * 1024),
                16, 0, 0);
        }
    };
    // frag read: operand op, 32-row group g (0..7), k-slice kk (0..1)
    auto frag = [&](int buf, int op, int g, int kk) -> f16x8 {
        return *(const f16x8*)(sm + buf * 65536 + op * 16384 + g * 2048 +
                               (kk * 2 + hl) * 512 + l31 * 16);
    };

    f32x16 acc[4][2];
#pragma unroll
    for (int fm = 0; fm < 4; ++fm)
#pragma unroll
        for (int fn = 0; fn < 2; ++fn)
#pragma unroll
            for (int q = 0; q < 16; ++q) acc[fm][fn][q] = 0.0f;

    const int nt = D / 32;   // 64
    int cbuf = 0;

    stage4(0, 0, 0);
    stage4(0, 0, 1);
    asm volatile("s_waitcnt vmcnt(0)" ::: "memory");
    __builtin_amdgcn_s_barrier();

#pragma unroll 1
    for (int t = 0; t < nt; ++t) {
        const int nk = (t + 1) * 32;

        // B-frags for the whole tile (8 reads)
        f16x8 Bh_[2][2], Bl_[2][2];
#pragma unroll
        for (int fn = 0; fn < 2; ++fn)
#pragma unroll
            for (int kk = 0; kk < 2; ++kk) {
                Bh_[fn][kk] = frag(cbuf, 2, wc * 2 + fn, kk);
                Bl_[fn][kk] = frag(cbuf, 3, wc * 2 + fn, kk);
            }

#pragma unroll
        for (int fm = 0; fm < 4; ++fm) {
            f16x8 ah0 = frag(cbuf, 0, wr * 4 + fm, 0);
            f16x8 ah1 = frag(cbuf, 0, wr * 4 + fm, 1);
            f16x8 al0 = frag(cbuf, 1, wr * 4 + fm, 0);
            f16x8 al1 = frag(cbuf, 1, wr * 4 + fm, 1);
            if (fm < 2 && t + 1 < nt) stage4(cbuf ^ 1, nk, fm);
            __builtin_amdgcn_s_barrier();
            __builtin_amdgcn_s_setprio(1);
#pragma unroll
            for (int fn = 0; fn < 2; ++fn) {
                acc[fm][fn] = __builtin_amdgcn_mfma_f32_32x32x16_f16(ah0, Bh_[fn][0], acc[fm][fn], 0, 0, 0);
                acc[fm][fn] = __builtin_amdgcn_mfma_f32_32x32x16_f16(ah0, Bl_[fn][0], acc[fm][fn], 0, 0, 0);
                acc[fm][fn] = __builtin_amdgcn_mfma_f32_32x32x16_f16(al0, Bh_[fn][0], acc[fm][fn], 0, 0, 0);
                acc[fm][fn] = __builtin_amdgcn_mfma_f32_32x32x16_f16(ah1, Bh_[fn][1], acc[fm][fn], 0, 0, 0);
                acc[fm][fn] = __builtin_amdgcn_mfma_f32_32x32x16_f16(ah1, Bl_[fn][1], acc[fm][fn], 0, 0, 0);
                acc[fm][fn] = __builtin_amdgcn_mfma_f32_32x32x16_f16(al1, Bh_[fn][1], acc[fm][fn], 0, 0, 0);
            }
            __builtin_amdgcn_s_setprio(0);
        }
        asm volatile("s_waitcnt vmcnt(0)" ::: "memory");
        __builtin_amdgcn_s_barrier();
        cbuf ^= 1;
    }

    // ---- fused argmax epilogue ----
    // 32x32 C/D layout: col = lane&31, row = (reg&3) + 8*(reg>>2) + 4*(lane>>5)
#pragma unroll
    for (int fm = 0; fm < 4; ++fm)
#pragma unroll
        for (int j = 0; j < 16; ++j) {
            const int row = bm + wr * 128 + fm * 32 + (j & 3) + 8 * (j >> 2) + 4 * hl;
            float v0 = acc[fm][0][j];
            float v1 = acc[fm][1][j];
            const int c0 = bn + wc * 64 + l31;
            float bv; int bc;
            if (v1 > v0) { bv = v1; bc = c0 + 32; } else { bv = v0; bc = c0; }
            unsigned long long packed =
                ((unsigned long long)fkey(bv) << 32) |
                (unsigned long long)(0xFFFFFFFFu - (unsigned int)bc);
#pragma unroll
            for (int m = 1; m < 32; m <<= 1) {
                unsigned long long o = __shfl_xor(packed, m);
                if (o > packed) packed = o;
            }
            if (l31 == 0) atomicMax(&best[row], packed);
        }
}

// ============================================================
// Fallback (small ws): round-1 fp32 kernel, known-passing.
// ============================================================
#define FBK 16
#define FTM 8
#define FTN 8

__global__ __launch_bounds__(256) void gemm_argmax_fp32_kernel(
    const float* __restrict__ A, const float* __restrict__ B,
    unsigned long long* __restrict__ best, int N, int D, int V)
{
    __shared__ float As[FBK][128 + 4];
    __shared__ float Bs[FBK][128 + 4];

    const int tid = threadIdx.x;
    const int tx = tid & 15;
    const int ty = tid >> 4;
    const int bm = blockIdx.y * 128;
    const int bn = blockIdx.x * 128;

    const int arow  = tid >> 2;
    const int acol4 = tid & 3;
    const int brow  = tid >> 5;
    const int bcol4 = tid & 31;

    float acc[FTM][FTN];
#pragma unroll
    for (int i = 0; i < FTM; ++i)
#pragma unroll
        for (int j = 0; j < FTN; ++j) acc[i][j] = 0.0f;

    for (int k0 = 0; k0 < D; k0 += FBK) {
        float4 a0 = *reinterpret_cast<const float4*>(&A[(size_t)(bm + arow) * D + k0 + acol4 * 4]);
        float4 a1 = *reinterpret_cast<const float4*>(&A[(size_t)(bm + arow + 64) * D + k0 + acol4 * 4]);
        float4 b0 = *reinterpret_cast<const float4*>(&B[(size_t)(k0 + brow) * V + bn + bcol4 * 4]);
        float4 b1 = *reinterpret_cast<const float4*>(&B[(size_t)(k0 + brow + 8) * V + bn + bcol4 * 4]);

        As[acol4 * 4 + 0][arow] = a0.x;
        As[acol4 * 4 + 1][arow] = a0.y;
        As[acol4 * 4 + 2][arow] = a0.z;
        As[acol4 * 4 + 3][arow] = a0.w;
        As[acol4 * 4 + 0][arow + 64] = a1.x;
        As[acol4 * 4 + 1][arow + 64] = a1.y;
        As[acol4 * 4 + 2][arow + 64] = a1.z;
        As[acol4 * 4 + 3][arow + 64] = a1.w;
        *reinterpret_cast<float4*>(&Bs[brow][bcol4 * 4]) = b0;
        *reinterpret_cast<float4*>(&Bs[brow + 8][bcol4 * 4]) = b1;

        __syncthreads();
#pragma unroll
        for (int kk = 0; kk < FBK; ++kk) {
            float4 av0 = *reinterpret_cast<const float4*>(&As[kk][ty * FTM]);
            float4 av1 = *reinterpret_cast<const float4*>(&As[kk][ty * FTM + 4]);
            float4 bv0 = *reinterpret_cast<const float4*>(&Bs[kk][tx * FTN]);
            float4 bv1 = *reinterpret_cast<const float4*>(&Bs[kk][tx * FTN + 4]);
            float a[FTM] = {av0.x, av0.y, av0.z, av0.w, av1.x, av1.y, av1.z, av1.w};
            float b[FTN] = {bv0.x, bv0.y, bv0.z, bv0.w, bv1.x, bv1.y, bv1.z, bv1.w};
#pragma unroll
            for (int i = 0; i < FTM; ++i)
#pragma unroll
                for (int j = 0; j < FTN; ++j)
                    acc[i][j] = fmaf(a[i], b[j], acc[i][j]);
        }
        __syncthreads();
    }

#pragma unroll
    for (int i = 0; i < FTM; ++i) {
        float bv = acc[i][0];
        int bc = bn + tx * FTN;
#pragma unroll
        for (int j = 1; j < FTN; ++j) {
            float v = acc[i][j];
            int c = bn + tx * FTN + j;
            if (v > bv) { bv = v; bc = c; }
        }
        unsigned long long packed =
            ((unsigned long long)fkey(bv) << 32) |
            (unsigned long long)(0xFFFFFFFFu - (unsigned int)bc);
#pragma unroll
        for (int m = 1; m < 16; m <<= 1) {
            unsigned long long o = __shfl_xor(packed, m, 16);
            if (o > packed) packed = o;
        }
        if (tx == 0) atomicMax(&best[bm + ty * FTM + i], packed);
    }
}

__global__ void decode_kernel(const unsigned long long* __restrict__ best,
                              float* __restrict__ out, int N)
{
    int i = blockIdx.x * blockDim.x + threadIdx.x;
    if (i < N) {
        unsigned int inv = (unsigned int)(best[i] & 0xFFFFFFFFull);
        out[i] = (float)(0xFFFFFFFFu - inv);
    }
}

extern "C" void kernel_launch(void* const* d_in, const int* in_sizes, int n_in,
                              void* d_out, int out_size, void* d_ws, size_t ws_size,
                              hipStream_t stream) {
    const float* A = (const float*)d_in[0];   // x  [N, D]
    const float* B = (const float*)d_in[1];   // di [D, V]
    float* out = (float*)d_out;

    const int N = out_size;                   // 16384
    const int D = in_sizes[0] / N;            // 2048
    const int V = in_sizes[1] / D;            // 8192

    const size_t szX = (size_t)N * D * sizeof(_Float16);   // 64 MB
    const size_t szD = (size_t)D * V * sizeof(_Float16);   // 32 MB
    const size_t need = 2 * szX + 2 * szD + (size_t)N * 8;

    if (ws_size >= need) {
        char* wsp = (char*)d_ws;
        _Float16* Xh  = (_Float16*)(wsp);
        _Float16* Xl  = (_Float16*)(wsp + szX);
        _Float16* DhT = (_Float16*)(wsp + 2 * szX);
        _Float16* DlT = (_Float16*)(wsp + 2 * szX + szD);
        unsigned long long* best = (unsigned long long*)(wsp + 2 * szX + 2 * szD);

        static int attr_done = 0;   // host-side, deterministic, idempotent
        if (!attr_done) {
            hipFuncSetAttribute((const void*)gemm_f16x3_argmax_256,
                                hipFuncAttributeMaxDynamicSharedMemorySize, 131072);
            attr_done = 1;
        }

        hipMemsetAsync(best, 0, (size_t)N * 8, stream);
        prep_x_kernel<<<(int)(((size_t)N * D) / (256 * 8)), 256, 0, stream>>>(A, Xh, Xl);
        prep_di_kernel<<<dim3(V / 64, D / 32), 256, 0, stream>>>(B, DhT, DlT, D, V);
        gemm_f16x3_argmax_256<<<(N / 256) * (V / 256), 512, 131072, stream>>>(
            Xh, Xl, DhT, DlT, best, N, D, V);
        decode_kernel<<<(N + 255) / 256, 256, 0, stream>>>(best, out, N);
    } else {
        unsigned long long* best = (unsigned long long*)d_ws;
        hipMemsetAsync(best, 0, (size_t)N * sizeof(unsigned long long), stream);
        gemm_argmax_fp32_kernel<<<dim3(V / 128, N / 128), 256, 0, stream>>>(A, B, best, N, D, V);
        decode_kernel<<<(N + 255) / 256, 256, 0, stream>>>(best, out, N);
    }
}

// Round 6
// 806.166 us; speedup vs baseline: 2.6227x; 2.6227x over previous
//
#include <hip/hip_runtime.h>

typedef _Float16 f16x8 __attribute__((ext_vector_type(8)));
typedef float f32x4 __attribute__((ext_vector_type(4)));

__device__ __forceinline__ unsigned int fkey(float f) {
    unsigned int u = __float_as_uint(f);
    return u ^ ((u & 0x80000000u) ? 0xFFFFFFFFu : 0x80000000u);
}
__device__ __forceinline__ float unkey(unsigned int k) {
    unsigned int u = (k & 0x80000000u) ? (k ^ 0x80000000u) : ~k;
    return __uint_as_float(u);
}

// ============================================================
// Prep: split fp32 -> (hi, lo) f16 pairs. x row-major; di transposed.
// ============================================================
__global__ __launch_bounds__(256) void prep_x_kernel(
    const float* __restrict__ x, _Float16* __restrict__ Xh,
    _Float16* __restrict__ Xl)
{
    size_t base = ((size_t)blockIdx.x * 256 + threadIdx.x) * 8;
    float4 a0 = *(const float4*)(x + base);
    float4 a1 = *(const float4*)(x + base + 4);
    float v[8] = {a0.x, a0.y, a0.z, a0.w, a1.x, a1.y, a1.z, a1.w};
    f16x8 h, l;
#pragma unroll
    for (int j = 0; j < 8; ++j) {
        _Float16 hh = (_Float16)v[j];
        h[j] = hh;
        l[j] = (_Float16)(v[j] - (float)hh);
    }
    *(f16x8*)(Xh + base) = h;
    *(f16x8*)(Xl + base) = l;
}

__global__ __launch_bounds__(256) void prep_di_kernel(
    const float* __restrict__ di, _Float16* __restrict__ DhT,
    _Float16* __restrict__ DlT, int D, int V)
{
    int v  = blockIdx.x * 64 + (threadIdx.x & 63);
    int d0 = blockIdx.y * 32 + (threadIdx.x >> 6) * 8;
    f16x8 h, l;
#pragma unroll
    for (int j = 0; j < 8; ++j) {
        float val = di[(size_t)(d0 + j) * V + v];
        _Float16 hh = (_Float16)val;
        h[j] = hh;
        l[j] = (_Float16)(val - (float)hh);
    }
    *(f16x8*)(DhT + (size_t)v * D + d0) = h;
    *(f16x8*)(DlT + (size_t)v * D + d0) = l;
}

// ============================================================
// Fast pass: single-term f16 GEMM Xh * DhT^T, tile 128x256, BK=64,
// 4 waves (1x4), per-wave 128x64 (8x4 16x16x32 frags).
// Round-3-proven staging: global_load_lds w=16, linear LDS dest,
// XOR swizzle on per-lane GLOBAL source (slot^row within 128B rows),
// matching XOR on ds_read -> measured 0 bank conflicts.
// Epilogue: top-2 per (row, 64-col wave slice) -> cand[N][V/256][4][2],
// packed u64 (fkey(score)<<32 | ~col), no atomics.
// ============================================================
__global__ __launch_bounds__(256, 2) void gemm_f16_fast_top2(
    const _Float16* __restrict__ Xh, const _Float16* __restrict__ DhT,
    unsigned long long* __restrict__ cand, int N, int D, int V)
{
    __shared__ __align__(16) unsigned char smbuf[49152];  // A 16KB | B 32KB
    unsigned char* smA = smbuf;
    unsigned char* smB = smbuf + 16384;

    const int tid = threadIdx.x;
    const int w = tid >> 6, lane = tid & 63;
    const int lm = lane & 15, lg = lane >> 4;
    const int wc = w;                       // 1x4 wave grid (cols)

    // bijective XCD swizzle (4096 blocks, % 8 == 0)
    const int cpx = gridDim.x >> 3;
    const int swz = (blockIdx.x & 7) * cpx + (blockIdx.x >> 3);
    const int bm = (swz >> 5) * 128;        // 128 m-tiles
    const int bn = (swz & 31) * 256;        // 32 n-tiles

    // staging: chunk = 8 rows x 128B; lane -> row l>>3, phys slot l&7,
    // source k-slot pre-swizzled: (l&7) ^ (l>>3)
    const int ri  = lane >> 3;
    const int sl8 = ((lane & 7) ^ ri) * 8;  // f16 offset within 64-k row

    f32x4 acc[8][4];
#pragma unroll
    for (int fm = 0; fm < 8; ++fm)
#pragma unroll
        for (int fn = 0; fn < 4; ++fn) acc[fm][fn] = (f32x4){0.f, 0.f, 0.f, 0.f};

    const int nt = D / 64;   // 32
#pragma unroll 1
    for (int t = 0; t < nt; ++t) {
        const int k0 = t * 64;
        // ---- stage: 48 chunks (A:16, B:32), 12 per wave ----
#pragma unroll
        for (int i = 0; i < 12; ++i) {
            const int ch = w * 12 + i;
            if (ch < 16) {
                __builtin_amdgcn_global_load_lds(
                    (const __attribute__((address_space(1))) void*)
                        (Xh + (size_t)(bm + ch * 8 + ri) * D + k0 + sl8),
                    (__attribute__((address_space(3))) void*)(smA + ch * 1024),
                    16, 0, 0);
            } else {
                const int cb = ch - 16;
                __builtin_amdgcn_global_load_lds(
                    (const __attribute__((address_space(1))) void*)
                        (DhT + (size_t)(bn + cb * 8 + ri) * D + k0 + sl8),
                    (__attribute__((address_space(3))) void*)(smB + cb * 1024),
                    16, 0, 0);
            }
        }
        __syncthreads();   // drains vmcnt before barrier

#pragma unroll
        for (int kk = 0; kk < 2; ++kk) {
            const int so = ((kk * 4 + lg) ^ (lm & 7)) * 16;
            f16x8 bfr[4];
#pragma unroll
            for (int fn = 0; fn < 4; ++fn)
                bfr[fn] = *(const f16x8*)(smB + (wc * 64 + fn * 16 + lm) * 128 + so);
#pragma unroll
            for (int fm = 0; fm < 8; ++fm) {
                f16x8 a = *(const f16x8*)(smA + (fm * 16 + lm) * 128 + so);
#pragma unroll
                for (int fn = 0; fn < 4; ++fn)
                    acc[fm][fn] = __builtin_amdgcn_mfma_f32_16x16x32_f16(
                        a, bfr[fn], acc[fm][fn], 0, 0, 0);
            }
        }
        if (t + 1 < nt) __syncthreads();
    }

    // ---- epilogue: top-2 per (row, this wave's 64 cols) ----
    const int nblk = V >> 8;
    const int blkn = bn >> 8;
#pragma unroll
    for (int fm = 0; fm < 8; ++fm)
#pragma unroll
        for (int j = 0; j < 4; ++j) {
            unsigned long long p[4];
#pragma unroll
            for (int fn = 0; fn < 4; ++fn) {
                const int col = bn + wc * 64 + fn * 16 + lm;
                p[fn] = ((unsigned long long)fkey(acc[fm][fn][j]) << 32) |
                        (unsigned long long)(0xFFFFFFFFu - (unsigned int)col);
            }
            unsigned long long t1 = p[0] > p[1] ? p[0] : p[1];
            unsigned long long t2 = p[0] > p[1] ? p[1] : p[0];
#pragma unroll
            for (int fn = 2; fn < 4; ++fn) {
                if (p[fn] > t1) { t2 = t1; t1 = p[fn]; }
                else if (p[fn] > t2) t2 = p[fn];
            }
#pragma unroll
            for (int m = 1; m < 16; m <<= 1) {
                unsigned long long o1 = __shfl_xor(t1, m, 16);
                unsigned long long o2 = __shfl_xor(t2, m, 16);
                unsigned long long n1 = t1 > o1 ? t1 : o1;
                unsigned long long lo = t1 > o1 ? o1 : t1;
                unsigned long long m2 = t2 > o2 ? t2 : o2;
                t2 = lo > m2 ? lo : m2;
                t1 = n1;
            }
            if (lm == 0) {
                const int row = bm + fm * 16 + lg * 4 + j;
                size_t ci = (((size_t)row * nblk + blkn) * 4 + wc) * 2;
                cand[ci] = t1;
                cand[ci + 1] = t2;
            }
        }
}

// ============================================================
// Refine: one wave per row. Global approx max over cand; if any other
// candidate within DELTA, rescore those exactly (4-term f16 fp32 dot).
// ============================================================
#define DELTA 0.5f

__global__ __launch_bounds__(256) void refine_kernel(
    const unsigned long long* __restrict__ cand,
    const _Float16* __restrict__ Xh, const _Float16* __restrict__ Xl,
    const _Float16* __restrict__ DhT, const _Float16* __restrict__ DlT,
    float* __restrict__ out, int N, int D, int V)
{
    const int w = threadIdx.x >> 6, lane = threadIdx.x & 63;
    const int r = blockIdx.x * 4 + w;
    if (r >= N) return;

    const int nent = (V >> 8) * 8;          // 256 entries per row
    const unsigned long long* cr = cand + (size_t)r * nent;

    unsigned long long p[4];
#pragma unroll
    for (int i = 0; i < 4; ++i) p[i] = cr[lane * 4 + i];

    unsigned long long pmax = p[0];
#pragma unroll
    for (int i = 1; i < 4; ++i) if (p[i] > pmax) pmax = p[i];
#pragma unroll
    for (int m = 1; m < 64; m <<= 1) {
        unsigned long long o = __shfl_xor(pmax, m);
        if (o > pmax) pmax = o;
    }

    const float s1 = unkey((unsigned int)(pmax >> 32));
    const unsigned int kthr = fkey(s1 - DELTA);

    int cnt = 0;
    unsigned long long masks[4];
#pragma unroll
    for (int i = 0; i < 4; ++i) {
        masks[i] = __ballot((unsigned int)(p[i] >> 32) >= kthr);
        cnt += __popcll(masks[i]);
    }

    if (cnt <= 1) {
        if (lane == 0)
            out[r] = (float)(0xFFFFFFFFu - (unsigned int)(pmax & 0xFFFFFFFFull));
        return;
    }

    // rescore each qualifying candidate exactly
    const f16x8* xh = (const f16x8*)(Xh + (size_t)r * D) + lane * 4;
    const f16x8* xl = (const f16x8*)(Xl + (size_t)r * D) + lane * 4;
    float xbuf[32];
#pragma unroll
    for (int q = 0; q < 4; ++q) {
        f16x8 h = xh[q], l = xl[q];
#pragma unroll
        for (int e = 0; e < 8; ++e) xbuf[q * 8 + e] = (float)h[e] + (float)l[e];
    }

    unsigned long long bestp = 0;
    for (int i = 0; i < 4; ++i) {
        unsigned long long mask = masks[i];
        while (mask) {
            const int src = __ffsll((unsigned long long)mask) - 1;
            mask &= mask - 1;
            const unsigned long long cp = __shfl(p[i], src);
            const int col = (int)(0xFFFFFFFFu - (unsigned int)(cp & 0xFFFFFFFFull));

            const f16x8* dh = (const f16x8*)(DhT + (size_t)col * D) + lane * 4;
            const f16x8* dl = (const f16x8*)(DlT + (size_t)col * D) + lane * 4;
            float s = 0.0f;
#pragma unroll
            for (int q = 0; q < 4; ++q) {
                f16x8 h = dh[q], l = dl[q];
#pragma unroll
                for (int e = 0; e < 8; ++e)
                    s = fmaf(xbuf[q * 8 + e], (float)h[e] + (float)l[e], s);
            }
#pragma unroll
            for (int m = 1; m < 64; m <<= 1) s += __shfl_xor(s, m);

            const unsigned long long pp =
                ((unsigned long long)fkey(s) << 32) |
                (unsigned long long)(0xFFFFFFFFu - (unsigned int)col);
            if (pp > bestp) bestp = pp;
        }
    }
    if (lane == 0)
        out[r] = (float)(0xFFFFFFFFu - (unsigned int)(bestp & 0xFFFFFFFFull));
}

// ============================================================
// Mid fallback (ws >= 192MB): round-3 3-term kernel, known 1.78ms.
// ============================================================
__global__ __launch_bounds__(256, 2) void gemm_f16x3_argmax_kernel(
    const _Float16* __restrict__ Xh, const _Float16* __restrict__ Xl,
    const _Float16* __restrict__ DhT, const _Float16* __restrict__ DlT,
    unsigned long long* __restrict__ best, int N, int D, int V)
{
    __shared__ __align__(16) unsigned char sm[4 * 128 * 128];

    const int tid = threadIdx.x;
    const int w = tid >> 6, lane = tid & 63;
    const int wr = w >> 1, wc = w & 1;
    const int lm = lane & 15, lg = lane >> 4;

    const int nwg = gridDim.x, cpx = nwg >> 3;
    const int bid = blockIdx.x;
    const int swz = (bid & 7) * cpx + (bid >> 3);
    const int bm = (swz >> 6) * 128;
    const int bn = (swz & 63) * 128;

    const int ri  = lane >> 3;
    const int sl8 = ((lane & 7) ^ ri) * 8;

    const _Float16* srcs[4] = {
        Xh  + (size_t)(bm + ri) * D + sl8,
        Xl  + (size_t)(bm + ri) * D + sl8,
        DhT + (size_t)(bn + ri) * D + sl8,
        DlT + (size_t)(bn + ri) * D + sl8 };

    f32x4 acc[4][4];
#pragma unroll
    for (int fm = 0; fm < 4; ++fm)
#pragma unroll
        for (int fn = 0; fn < 4; ++fn) acc[fm][fn] = (f32x4){0.f, 0.f, 0.f, 0.f};

    const int nt = D / 64;
#pragma unroll 1
    for (int t = 0; t < nt; ++t) {
        const int k0 = t * 64;
#pragma unroll
        for (int tt = 0; tt < 4; ++tt) {
#pragma unroll
            for (int i = 0; i < 4; ++i) {
                const int c = w + i * 4;
                __builtin_amdgcn_global_load_lds(
                    (const __attribute__((address_space(1))) void*)
                        (srcs[tt] + (size_t)(c * 8) * D + k0),
                    (__attribute__((address_space(3))) void*)
                        (sm + tt * 16384 + c * 1024),
                    16, 0, 0);
            }
        }
        __syncthreads();

#pragma unroll
        for (int kk = 0; kk < 2; ++kk) {
            f16x8 ah[4], al[4], bh[4], bl[4];
            const int so = ((kk * 4 + lg) ^ (lm & 7)) * 16;
#pragma unroll
            for (int f = 0; f < 4; ++f) {
                const int ar = wr * 64 + f * 16 + lm;
                const int br = wc * 64 + f * 16 + lm;
                ah[f] = *(const f16x8*)(sm +         ar * 128 + so);
                al[f] = *(const f16x8*)(sm + 16384 + ar * 128 + so);
                bh[f] = *(const f16x8*)(sm + 32768 + br * 128 + so);
                bl[f] = *(const f16x8*)(sm + 49152 + br * 128 + so);
            }
#pragma unroll
            for (int fm = 0; fm < 4; ++fm)
#pragma unroll
                for (int fn = 0; fn < 4; ++fn) {
                    acc[fm][fn] = __builtin_amdgcn_mfma_f32_16x16x32_f16(ah[fm], bh[fn], acc[fm][fn], 0, 0, 0);
                    acc[fm][fn] = __builtin_amdgcn_mfma_f32_16x16x32_f16(ah[fm], bl[fn], acc[fm][fn], 0, 0, 0);
                    acc[fm][fn] = __builtin_amdgcn_mfma_f32_16x16x32_f16(al[fm], bh[fn], acc[fm][fn], 0, 0, 0);
                }
        }
        if (t + 1 < nt) __syncthreads();
    }

#pragma unroll
    for (int fm = 0; fm < 4; ++fm)
#pragma unroll
        for (int j = 0; j < 4; ++j) {
            const int row = bm + wr * 64 + fm * 16 + lg * 4 + j;
            float bv = acc[fm][0][j];
            int   bc = bn + wc * 64 + lm;
#pragma unroll
            for (int fn = 1; fn < 4; ++fn) {
                float vv = acc[fm][fn][j];
                int   cc = bn + wc * 64 + fn * 16 + lm;
                if (vv > bv) { bv = vv; bc = cc; }
            }
            unsigned long long packed =
                ((unsigned long long)fkey(bv) << 32) |
                (unsigned long long)(0xFFFFFFFFu - (unsigned int)bc);
#pragma unroll
            for (int m = 1; m < 16; m <<= 1) {
                unsigned long long o = __shfl_xor(packed, m, 16);
                if (o > packed) packed = o;
            }
            if (lm == 0) atomicMax(&best[row], packed);
        }
}

// ============================================================
// Last fallback: fp32 VALU kernel (round 1).
// ============================================================
#define FBK 16
#define FTM 8
#define FTN 8

__global__ __launch_bounds__(256) void gemm_argmax_fp32_kernel(
    const float* __restrict__ A, const float* __restrict__ B,
    unsigned long long* __restrict__ best, int N, int D, int V)
{
    __shared__ float As[FBK][128 + 4];
    __shared__ float Bs[FBK][128 + 4];

    const int tid = threadIdx.x;
    const int tx = tid & 15;
    const int ty = tid >> 4;
    const int bm = blockIdx.y * 128;
    const int bn = blockIdx.x * 128;

    const int arow  = tid >> 2;
    const int acol4 = tid & 3;
    const int brow  = tid >> 5;
    const int bcol4 = tid & 31;

    float acc[FTM][FTN];
#pragma unroll
    for (int i = 0; i < FTM; ++i)
#pragma unroll
        for (int j = 0; j < FTN; ++j) acc[i][j] = 0.0f;

    for (int k0 = 0; k0 < D; k0 += FBK) {
        float4 a0 = *reinterpret_cast<const float4*>(&A[(size_t)(bm + arow) * D + k0 + acol4 * 4]);
        float4 a1 = *reinterpret_cast<const float4*>(&A[(size_t)(bm + arow + 64) * D + k0 + acol4 * 4]);
        float4 b0 = *reinterpret_cast<const float4*>(&B[(size_t)(k0 + brow) * V + bn + bcol4 * 4]);
        float4 b1 = *reinterpret_cast<const float4*>(&B[(size_t)(k0 + brow + 8) * V + bn + bcol4 * 4]);

        As[acol4 * 4 + 0][arow] = a0.x;
        As[acol4 * 4 + 1][arow] = a0.y;
        As[acol4 * 4 + 2][arow] = a0.z;
        As[acol4 * 4 + 3][arow] = a0.w;
        As[acol4 * 4 + 0][arow + 64] = a1.x;
        As[acol4 * 4 + 1][arow + 64] = a1.y;
        As[acol4 * 4 + 2][arow + 64] = a1.z;
        As[acol4 * 4 + 3][arow + 64] = a1.w;
        *reinterpret_cast<float4*>(&Bs[brow][bcol4 * 4]) = b0;
        *reinterpret_cast<float4*>(&Bs[brow + 8][bcol4 * 4]) = b1;

        __syncthreads();
#pragma unroll
        for (int kk = 0; kk < FBK; ++kk) {
            float4 av0 = *reinterpret_cast<const float4*>(&As[kk][ty * FTM]);
            float4 av1 = *reinterpret_cast<const float4*>(&As[kk][ty * FTM + 4]);
            float4 bv0 = *reinterpret_cast<const float4*>(&Bs[kk][tx * FTN]);
            float4 bv1 = *reinterpret_cast<const float4*>(&Bs[kk][tx * FTN + 4]);
            float a[FTM] = {av0.x, av0.y, av0.z, av0.w, av1.x, av1.y, av1.z, av1.w};
            float b[FTN] = {bv0.x, bv0.y, bv0.z, bv0.w, bv1.x, bv1.y, bv1.z, bv1.w};
#pragma unroll
            for (int i = 0; i < FTM; ++i)
#pragma unroll
                for (int j = 0; j < FTN; ++j)
                    acc[i][j] = fmaf(a[i], b[j], acc[i][j]);
        }
        __syncthreads();
    }

#pragma unroll
    for (int i = 0; i < FTM; ++i) {
        float bv = acc[i][0];
        int bc = bn + tx * FTN;
#pragma unroll
        for (int j = 1; j < FTN; ++j) {
            float v = acc[i][j];
            int c = bn + tx * FTN + j;
            if (v > bv) { bv = v; bc = c; }
        }
        unsigned long long packed =
            ((unsigned long long)fkey(bv) << 32) |
            (unsigned long long)(0xFFFFFFFFu - (unsigned int)bc);
#pragma unroll
        for (int m = 1; m < 16; m <<= 1) {
            unsigned long long o = __shfl_xor(packed, m, 16);
            if (o > packed) packed = o;
        }
        if (tx == 0) atomicMax(&best[bm + ty * FTM + i], packed);
    }
}

__global__ void decode_kernel(const unsigned long long* __restrict__ best,
                              float* __restrict__ out, int N)
{
    int i = blockIdx.x * blockDim.x + threadIdx.x;
    if (i < N) {
        unsigned int inv = (unsigned int)(best[i] & 0xFFFFFFFFull);
        out[i] = (float)(0xFFFFFFFFu - inv);
    }
}

extern "C" void kernel_launch(void* const* d_in, const int* in_sizes, int n_in,
                              void* d_out, int out_size, void* d_ws, size_t ws_size,
                              hipStream_t stream) {
    const float* A = (const float*)d_in[0];   // x  [N, D]
    const float* B = (const float*)d_in[1];   // di [D, V]
    float* out = (float*)d_out;

    const int N = out_size;                   // 16384
    const int D = in_sizes[0] / N;            // 2048
    const int V = in_sizes[1] / D;            // 8192

    const size_t szX = (size_t)N * D * sizeof(_Float16);   // 64 MB
    const size_t szD = (size_t)D * V * sizeof(_Float16);   // 32 MB
    const size_t candsz = (size_t)N * (V / 256) * 4 * 2 * 8;  // 32 MB
    const size_t need_fast = 2 * szX + 2 * szD + candsz;
    const size_t need_mid  = 2 * szX + 2 * szD + (size_t)N * 8;

    char* wsp = (char*)d_ws;
    _Float16* Xh  = (_Float16*)(wsp);
    _Float16* Xl  = (_Float16*)(wsp + szX);
    _Float16* DhT = (_Float16*)(wsp + 2 * szX);
    _Float16* DlT = (_Float16*)(wsp + 2 * szX + szD);

    if (ws_size >= need_fast) {
        unsigned long long* cand = (unsigned long long*)(wsp + 2 * szX + 2 * szD);

        prep_x_kernel<<<(int)(((size_t)N * D) / (256 * 8)), 256, 0, stream>>>(A, Xh, Xl);
        prep_di_kernel<<<dim3(V / 64, D / 32), 256, 0, stream>>>(B, DhT, DlT, D, V);
        gemm_f16_fast_top2<<<(N / 128) * (V / 256), 256, 0, stream>>>(
            Xh, DhT, cand, N, D, V);
        refine_kernel<<<(N + 3) / 4, 256, 0, stream>>>(
            cand, Xh, Xl, DhT, DlT, out, N, D, V);
    } else if (ws_size >= need_mid) {
        unsigned long long* best = (unsigned long long*)(wsp + 2 * szX + 2 * szD);
        hipMemsetAsync(best, 0, (size_t)N * 8, stream);
        prep_x_kernel<<<(int)(((size_t)N * D) / (256 * 8)), 256, 0, stream>>>(A, Xh, Xl);
        prep_di_kernel<<<dim3(V / 64, D / 32), 256, 0, stream>>>(B, DhT, DlT, D, V);
        gemm_f16x3_argmax_kernel<<<(N / 128) * (V / 128), 256, 0, stream>>>(
            Xh, Xl, DhT, DlT, best, N, D, V);
        decode_kernel<<<(N + 255) / 256, 256, 0, stream>>>(best, out, N);
    } else {
        unsigned long long* best = (unsigned long long*)d_ws;
        hipMemsetAsync(best, 0, (size_t)N * sizeof(unsigned long long), stream);
        gemm_argmax_fp32_kernel<<<dim3(V / 128, N / 128), 256, 0, stream>>>(A, B, best, N, D, V);
        decode_kernel<<<(N + 255) / 256, 256, 0, stream>>>(best, out, N);
    }
}

// Round 7
// 701.568 us; speedup vs baseline: 3.0137x; 1.1491x over previous
//
#include <hip/hip_runtime.h>

typedef _Float16 f16x8 __attribute__((ext_vector_type(8)));
typedef float f32x4 __attribute__((ext_vector_type(4)));

__device__ __forceinline__ unsigned int fkey(float f) {
    unsigned int u = __float_as_uint(f);
    return u ^ ((u & 0x80000000u) ? 0xFFFFFFFFu : 0x80000000u);
}
__device__ __forceinline__ float unkey(unsigned int k) {
    unsigned int u = (k & 0x80000000u) ? (k ^ 0x80000000u) : ~k;
    return __uint_as_float(u);
}

// OCP e4m3fn encode, round-to-nearest-even (manual: no intrinsic-semantics risk)
__device__ __forceinline__ unsigned int f32_to_e4m3(float f) {
    float a = fabsf(f);
    a = fminf(a, 448.0f);
    unsigned int s = (__float_as_uint(f) >> 24) & 0x80u;
    if (a < 0.015625f) {                       // denormal grid 2^-9
        int m = (int)rintf(a * 512.0f);        // 0..8
        return s | (unsigned int)m;            // m==8 -> 0x08 == 2^-6 exactly
    }
    int e = ilogbf(a);                         // -6..8
    float step = ldexpf(1.0f, e - 3);
    int q = (int)rintf(a / step);              // 8..16
    if (q == 16) { e += 1; q = 8; }
    return s | (unsigned int)(((e + 7) << 3) | (q - 8));   // 448 -> 0x7E (no NaN)
}

// ============================================================
// Prep: x fp32 -> Xq (fp8). 8 elems/thread.
// ============================================================
__global__ __launch_bounds__(256) void prep_x_q(
    const float* __restrict__ x, unsigned char* __restrict__ Xq)
{
    size_t base = ((size_t)blockIdx.x * 256 + threadIdx.x) * 8;
    float4 a0 = *(const float4*)(x + base);
    float4 a1 = *(const float4*)(x + base + 4);
    float v[8] = {a0.x, a0.y, a0.z, a0.w, a1.x, a1.y, a1.z, a1.w};
    unsigned long long b = 0;
#pragma unroll
    for (int j = 0; j < 8; ++j)
        b |= (unsigned long long)f32_to_e4m3(v[j]) << (8 * j);
    *(unsigned long long*)(Xq + base) = b;
}

// ============================================================
// Prep: di fp32 -> DqT (fp8, transposed) + DhT/DlT (f16 split, transposed)
// ============================================================
__global__ __launch_bounds__(256) void prep_di_q(
    const float* __restrict__ di, unsigned char* __restrict__ DqT,
    _Float16* __restrict__ DhT, _Float16* __restrict__ DlT, int D, int V)
{
    int v  = blockIdx.x * 64 + (threadIdx.x & 63);
    int d0 = blockIdx.y * 32 + (threadIdx.x >> 6) * 8;
    f16x8 h, l;
    unsigned long long b = 0;
#pragma unroll
    for (int j = 0; j < 8; ++j) {
        float val = di[(size_t)(d0 + j) * V + v];    // coalesced across lanes
        _Float16 hh = (_Float16)val;
        h[j] = hh;
        l[j] = (_Float16)(val - (float)hh);
        b |= (unsigned long long)f32_to_e4m3(val) << (8 * j);
    }
    *(unsigned long long*)(DqT + (size_t)v * D + d0) = b;
    *(f16x8*)(DhT + (size_t)v * D + d0) = h;
    *(f16x8*)(DlT + (size_t)v * D + d0) = l;
}

// ============================================================
// Fast pass: fp8 GEMM Xq * DqT^T, 256x256 tile, BK=64, 8 waves (2x4),
// per-wave 128x64 (8x4 16x16x32 fp8 frags), double-buffered LDS (2x32KB),
// ONE barrier per K-tile: stage(t+1) issued before compute(t), drain at
// the __syncthreads (compute covers staging latency).
// Staging: global_load_lds w=4 (4B granular), source pre-swizzled with
// 8-slot XOR over each 64B row -> ds_read_b64 frag reads conflict-free,
// and the 8B read IS the i64 MFMA operand (no repack).
// Epilogue: top-2 per (row, 64-col wave slice) -> cand, packed u64.
// ============================================================
__global__ __launch_bounds__(512, 1) void gemm_fp8_top2(
    const unsigned char* __restrict__ Xq, const unsigned char* __restrict__ DqT,
    unsigned long long* __restrict__ cand, int N, int D, int V)
{
    __shared__ __align__(16) unsigned char sm[65536];   // [buf][op][16KB]

    const int tid = threadIdx.x;
    const int w = tid >> 6, lane = tid & 63;
    const int wr = w >> 2, wc = w & 3;            // 2x4 wave grid
    const int lm = lane & 15, lg = lane >> 4;     // frag row / k-slot
    const int rch = lane >> 4;                    // staging: row in 4-row chunk
    const int sl  = lane & 15;                    // staging: 4B unit in 64B row

    // bijective XCD swizzle (2048 blocks % 8 == 0)
    const int cpx = gridDim.x >> 3;
    const int swz = (blockIdx.x & 7) * cpx + (blockIdx.x >> 3);
    const int bm = (swz >> 5) * 256;              // 64 m-tiles
    const int bn = (swz & 31) * 256;              // 32 n-tiles

    // wave w stages chunks g = w*16+i; op = g>>6 (A/B), cc = g&63 (4 rows x 64B)
    auto stage = [&](int buf, int k0) {
#pragma unroll
        for (int i = 0; i < 16; ++i) {
            const int g = w * 16 + i;
            const int op = g >> 6;
            const int cc = g & 63;
            const int row = cc * 4 + rch;
            const int slog = (sl >> 1) ^ (row & 7);         // pre-swizzled slot
            const unsigned char* src =
                (op ? DqT + (size_t)(bn + row) * D : Xq + (size_t)(bm + row) * D)
                + k0 + slog * 8 + (sl & 1) * 4;
            __builtin_amdgcn_global_load_lds(
                (const __attribute__((address_space(1))) void*)src,
                (__attribute__((address_space(3))) void*)
                    (sm + buf * 32768 + op * 16384 + cc * 256),
                4, 0, 0);
        }
    };
    // frag read: 8B at (row, k-slot kk*4+lg), phys slot = logical ^ (row&7)
    auto lda = [&](int buf, int op, int row, int kk) -> long {
        return *(const long*)(sm + buf * 32768 + op * 16384 + row * 64 +
                              (((kk << 2) | lg) ^ (lm & 7)) * 8);
    };

    f32x4 acc[8][4];
#pragma unroll
    for (int fm = 0; fm < 8; ++fm)
#pragma unroll
        for (int fn = 0; fn < 4; ++fn) acc[fm][fn] = (f32x4){0.f, 0.f, 0.f, 0.f};

    const int nt = D / 64;   // 32
    int cb = 0;

    stage(0, 0);
    __syncthreads();

#pragma unroll 1
    for (int t = 0; t < nt; ++t) {
        if (t + 1 < nt) stage(cb ^ 1, (t + 1) * 64);   // fire-and-forget
#pragma unroll
        for (int kk = 0; kk < 2; ++kk) {
            long bfr[4];
#pragma unroll
            for (int fn = 0; fn < 4; ++fn)
                bfr[fn] = lda(cb, 1, wc * 64 + fn * 16 + lm, kk);
#pragma unroll
            for (int fm = 0; fm < 8; ++fm) {
                long a = lda(cb, 0, wr * 128 + fm * 16 + lm, kk);
#pragma unroll
                for (int fn = 0; fn < 4; ++fn)
                    acc[fm][fn] = __builtin_amdgcn_mfma_f32_16x16x32_fp8_fp8(
                        a, bfr[fn], acc[fm][fn], 0, 0, 0);
            }
        }
        __syncthreads();   // drains vmcnt (staging) + lgkm; one barrier/tile
        cb ^= 1;
    }

    // ---- epilogue: top-2 per (row, this wave's 64 cols) ----
    // C/D layout: col = lane&15, row = (lane>>4)*4 + j
    const int nblk = V >> 8;
    const int blkn = bn >> 8;
#pragma unroll
    for (int fm = 0; fm < 8; ++fm)
#pragma unroll
        for (int j = 0; j < 4; ++j) {
            unsigned long long p[4];
#pragma unroll
            for (int fn = 0; fn < 4; ++fn) {
                const int col = bn + wc * 64 + fn * 16 + lm;
                p[fn] = ((unsigned long long)fkey(acc[fm][fn][j]) << 32) |
                        (unsigned long long)(0xFFFFFFFFu - (unsigned int)col);
            }
            unsigned long long t1 = p[0] > p[1] ? p[0] : p[1];
            unsigned long long t2 = p[0] > p[1] ? p[1] : p[0];
#pragma unroll
            for (int fn = 2; fn < 4; ++fn) {
                if (p[fn] > t1) { t2 = t1; t1 = p[fn]; }
                else if (p[fn] > t2) t2 = p[fn];
            }
#pragma unroll
            for (int m = 1; m < 16; m <<= 1) {
                unsigned long long o1 = __shfl_xor(t1, m, 16);
                unsigned long long o2 = __shfl_xor(t2, m, 16);
                unsigned long long n1 = t1 > o1 ? t1 : o1;
                unsigned long long lo = t1 > o1 ? o1 : t1;
                unsigned long long m2 = t2 > o2 ? t2 : o2;
                t2 = lo > m2 ? lo : m2;
                t1 = n1;
            }
            if (lm == 0) {
                const int row = bm + wr * 128 + fm * 16 + lg * 4 + j;
                size_t ci = (((size_t)row * nblk + blkn) * 4 + wc) * 2;
                cand[ci] = t1;
                cand[ci + 1] = t2;
            }
        }
}

// ============================================================
// Refine: one wave per row. fp8 noise sigma ~2.3 -> Delta = 16.5 (5 sigma).
// Rescore qualifiers exactly: fp32 x row (from d_in) dot (dh + dl).
// ============================================================
#define DELTA 16.5f

__global__ __launch_bounds__(256) void refine_kernel(
    const unsigned long long* __restrict__ cand,
    const float* __restrict__ X,
    const _Float16* __restrict__ DhT, const _Float16* __restrict__ DlT,
    float* __restrict__ out, int N, int D, int V)
{
    const int w = threadIdx.x >> 6, lane = threadIdx.x & 63;
    const int r = blockIdx.x * 4 + w;
    if (r >= N) return;

    const int nent = (V >> 8) * 8;          // 256 entries per row
    const unsigned long long* cr = cand + (size_t)r * nent;

    unsigned long long p[4];
#pragma unroll
    for (int i = 0; i < 4; ++i) p[i] = cr[lane * 4 + i];

    unsigned long long pmax = p[0];
#pragma unroll
    for (int i = 1; i < 4; ++i) if (p[i] > pmax) pmax = p[i];
#pragma unroll
    for (int m = 1; m < 64; m <<= 1) {
        unsigned long long o = __shfl_xor(pmax, m);
        if (o > pmax) pmax = o;
    }

    const float s1 = unkey((unsigned int)(pmax >> 32));
    const unsigned int kthr = fkey(s1 - DELTA);

    int cnt = 0;
    unsigned long long masks[4];
#pragma unroll
    for (int i = 0; i < 4; ++i) {
        masks[i] = __ballot((unsigned int)(p[i] >> 32) >= kthr);
        cnt += __popcll(masks[i]);
    }

    if (cnt <= 1) {
        if (lane == 0)
            out[r] = (float)(0xFFFFFFFFu - (unsigned int)(pmax & 0xFFFFFFFFull));
        return;
    }

    // exact rescore: fp32 x row, d = dh + dl (error ~2^-22)
    const float* xrow = X + (size_t)r * D;
    float xbuf[32];
#pragma unroll
    for (int q = 0; q < 8; ++q) {
        float4 xv = *(const float4*)(xrow + lane * 32 + q * 4);
        xbuf[q * 4 + 0] = xv.x; xbuf[q * 4 + 1] = xv.y;
        xbuf[q * 4 + 2] = xv.z; xbuf[q * 4 + 3] = xv.w;
    }

    unsigned long long bestp = 0;
    for (int i = 0; i < 4; ++i) {
        unsigned long long mask = masks[i];
        while (mask) {
            const int src = __ffsll((unsigned long long)mask) - 1;
            mask &= mask - 1;
            const unsigned long long cp = __shfl(p[i], src);
            const int col = (int)(0xFFFFFFFFu - (unsigned int)(cp & 0xFFFFFFFFull));

            const f16x8* dh = (const f16x8*)(DhT + (size_t)col * D) + lane * 4;
            const f16x8* dl = (const f16x8*)(DlT + (size_t)col * D) + lane * 4;
            float s = 0.0f;
#pragma unroll
            for (int q = 0; q < 4; ++q) {
                f16x8 h = dh[q], l = dl[q];
#pragma unroll
                for (int e = 0; e < 8; ++e)
                    s = fmaf(xbuf[q * 8 + e], (float)h[e] + (float)l[e], s);
            }
#pragma unroll
            for (int m = 1; m < 64; m <<= 1) s += __shfl_xor(s, m);

            const unsigned long long pp =
                ((unsigned long long)fkey(s) << 32) |
                (unsigned long long)(0xFFFFFFFFu - (unsigned int)col);
            if (pp > bestp) bestp = pp;
        }
    }
    if (lane == 0)
        out[r] = (float)(0xFFFFFFFFu - (unsigned int)(bestp & 0xFFFFFFFFull));
}

// ============================================================
// Last-resort fallback: fp32 VALU kernel (round 1, known-passing).
// ============================================================
#define FBK 16
#define FTM 8
#define FTN 8

__global__ __launch_bounds__(256) void gemm_argmax_fp32_kernel(
    const float* __restrict__ A, const float* __restrict__ B,
    unsigned long long* __restrict__ best, int N, int D, int V)
{
    __shared__ float As[FBK][128 + 4];
    __shared__ float Bs[FBK][128 + 4];

    const int tid = threadIdx.x;
    const int tx = tid & 15;
    const int ty = tid >> 4;
    const int bm = blockIdx.y * 128;
    const int bn = blockIdx.x * 128;

    const int arow  = tid >> 2;
    const int acol4 = tid & 3;
    const int brow  = tid >> 5;
    const int bcol4 = tid & 31;

    float acc[FTM][FTN];
#pragma unroll
    for (int i = 0; i < FTM; ++i)
#pragma unroll
        for (int j = 0; j < FTN; ++j) acc[i][j] = 0.0f;

    for (int k0 = 0; k0 < D; k0 += FBK) {
        float4 a0 = *reinterpret_cast<const float4*>(&A[(size_t)(bm + arow) * D + k0 + acol4 * 4]);
        float4 a1 = *reinterpret_cast<const float4*>(&A[(size_t)(bm + arow + 64) * D + k0 + acol4 * 4]);
        float4 b0 = *reinterpret_cast<const float4*>(&B[(size_t)(k0 + brow) * V + bn + bcol4 * 4]);
        float4 b1 = *reinterpret_cast<const float4*>(&B[(size_t)(k0 + brow + 8) * V + bn + bcol4 * 4]);

        As[acol4 * 4 + 0][arow] = a0.x;
        As[acol4 * 4 + 1][arow] = a0.y;
        As[acol4 * 4 + 2][arow] = a0.z;
        As[acol4 * 4 + 3][arow] = a0.w;
        As[acol4 * 4 + 0][arow + 64] = a1.x;
        As[acol4 * 4 + 1][arow + 64] = a1.y;
        As[acol4 * 4 + 2][arow + 64] = a1.z;
        As[acol4 * 4 + 3][arow + 64] = a1.w;
        *reinterpret_cast<float4*>(&Bs[brow][bcol4 * 4]) = b0;
        *reinterpret_cast<float4*>(&Bs[brow + 8][bcol4 * 4]) = b1;

        __syncthreads();
#pragma unroll
        for (int kk = 0; kk < FBK; ++kk) {
            float4 av0 = *reinterpret_cast<const float4*>(&As[kk][ty * FTM]);
            float4 av1 = *reinterpret_cast<const float4*>(&As[kk][ty * FTM + 4]);
            float4 bv0 = *reinterpret_cast<const float4*>(&Bs[kk][tx * FTN]);
            float4 bv1 = *reinterpret_cast<const float4*>(&Bs[kk][tx * FTN + 4]);
            float a[FTM] = {av0.x, av0.y, av0.z, av0.w, av1.x, av1.y, av1.z, av1.w};
            float b[FTN] = {bv0.x, bv0.y, bv0.z, bv0.w, bv1.x, bv1.y, bv1.z, bv1.w};
#pragma unroll
            for (int i = 0; i < FTM; ++i)
#pragma unroll
                for (int j = 0; j < FTN; ++j)
                    acc[i][j] = fmaf(a[i], b[j], acc[i][j]);
        }
        __syncthreads();
    }

#pragma unroll
    for (int i = 0; i < FTM; ++i) {
        float bv = acc[i][0];
        int bc = bn + tx * FTN;
#pragma unroll
        for (int j = 1; j < FTN; ++j) {
            float v = acc[i][j];
            int c = bn + tx * FTN + j;
            if (v > bv) { bv = v; bc = c; }
        }
        unsigned long long packed =
            ((unsigned long long)fkey(bv) << 32) |
            (unsigned long long)(0xFFFFFFFFu - (unsigned int)bc);
#pragma unroll
        for (int m = 1; m < 16; m <<= 1) {
            unsigned long long o = __shfl_xor(packed, m, 16);
            if (o > packed) packed = o;
        }
        if (tx == 0) atomicMax(&best[bm + ty * FTM + i], packed);
    }
}

__global__ void decode_kernel(const unsigned long long* __restrict__ best,
                              float* __restrict__ out, int N)
{
    int i = blockIdx.x * blockDim.x + threadIdx.x;
    if (i < N) {
        unsigned int inv = (unsigned int)(best[i] & 0xFFFFFFFFull);
        out[i] = (float)(0xFFFFFFFFu - inv);
    }
}

extern "C" void kernel_launch(void* const* d_in, const int* in_sizes, int n_in,
                              void* d_out, int out_size, void* d_ws, size_t ws_size,
                              hipStream_t stream) {
    const float* A = (const float*)d_in[0];   // x  [N, D]
    const float* B = (const float*)d_in[1];   // di [D, V]
    float* out = (float*)d_out;

    const int N = out_size;                   // 16384
    const int D = in_sizes[0] / N;            // 2048
    const int V = in_sizes[1] / D;            // 8192

    const size_t szXq = (size_t)N * D;                       // 32 MB fp8
    const size_t szDq = (size_t)D * V;                       // 16 MB fp8
    const size_t szDh = (size_t)D * V * sizeof(_Float16);    // 32 MB
    const size_t candsz = (size_t)N * (V / 256) * 4 * 2 * 8; // 32 MB
    const size_t need = szXq + szDq + 2 * szDh + candsz;     // ~146 MB

    if (ws_size >= need) {
        char* wsp = (char*)d_ws;
        unsigned char* Xq  = (unsigned char*)(wsp);
        unsigned char* DqT = (unsigned char*)(wsp + szXq);
        _Float16* DhT = (_Float16*)(wsp + szXq + szDq);
        _Float16* DlT = (_Float16*)(wsp + szXq + szDq + szDh);
        unsigned long long* cand =
            (unsigned long long*)(wsp + szXq + szDq + 2 * szDh);

        prep_x_q<<<(int)(((size_t)N * D) / (256 * 8)), 256, 0, stream>>>(A, Xq);
        prep_di_q<<<dim3(V / 64, D / 32), 256, 0, stream>>>(B, DqT, DhT, DlT, D, V);
        gemm_fp8_top2<<<(N / 256) * (V / 256), 512, 0, stream>>>(
            Xq, DqT, cand, N, D, V);
        refine_kernel<<<(N + 3) / 4, 256, 0, stream>>>(
            cand, A, DhT, DlT, out, N, D, V);
    } else {
        unsigned long long* best = (unsigned long long*)d_ws;
        hipMemsetAsync(best, 0, (size_t)N * sizeof(unsigned long long), stream);
        gemm_argmax_fp32_kernel<<<dim3(V / 128, N / 128), 256, 0, stream>>>(A, B, best, N, D, V);
        decode_kernel<<<(N + 255) / 256, 256, 0, stream>>>(best, out, N);
    }
}